// Round 9
// baseline (169.052 us; speedup 1.0000x reference)
//
#include <hip/hip_runtime.h>

#define NNODE 2048
#define DD    512
#define HHID  256
#define LLAT  16
#define H2    32   // 2L

typedef __attribute__((ext_vector_type(8))) short  short8;
typedef __attribute__((ext_vector_type(4))) float  f32x4;

__device__ __forceinline__ unsigned short f2bf(float x) {
    unsigned int u = __float_as_uint(x);
    unsigned int r = (u + 0x7fffu + ((u >> 16) & 1u)) >> 16;  // RNE
    return (unsigned short)r;
}
__device__ __forceinline__ float bf2f(unsigned short u) {
    return __uint_as_float(((unsigned int)u) << 16);
}
__device__ __forceinline__ uint4 cvt8u(const float* p) {   // 8 fp32 -> 8 bf16 packed
    float4 f0 = *(const float4*)p;
    float4 f1 = *(const float4*)(p + 4);
    uint4 r;
    unsigned short* s = (unsigned short*)&r;
    s[0] = f2bf(f0.x); s[1] = f2bf(f0.y); s[2] = f2bf(f0.z); s[3] = f2bf(f0.w);
    s[4] = f2bf(f1.x); s[5] = f2bf(f1.y); s[6] = f2bf(f1.z); s[7] = f2bf(f1.w);
    return r;
}
// sum 4 bf16 partials (stride 524288 elem) at element offset off -> bf16x8
__device__ __forceinline__ uint4 sum4bf(const unsigned short* base, size_t off) {
    uint4 a = *(const uint4*)(base + off);
    uint4 b = *(const uint4*)(base + off + 524288);
    uint4 c = *(const uint4*)(base + off + 1048576);
    uint4 d = *(const uint4*)(base + off + 1572864);
    const unsigned short* pa = (const unsigned short*)&a;
    const unsigned short* pb = (const unsigned short*)&b;
    const unsigned short* pc = (const unsigned short*)&c;
    const unsigned short* pd = (const unsigned short*)&d;
    uint4 r;
    unsigned short* pr = (unsigned short*)&r;
    #pragma unroll
    for (int e = 0; e < 8; ++e)
        pr[e] = f2bf((bf2f(pa[e]) + bf2f(pb[e])) + (bf2f(pc[e]) + bf2f(pd[e])));
    return r;
}

// ---- K1: prologue A->bf16; XWpb[s][h][n] = bf16 partial W1 @ X^T (splitK=4) -----
__global__ __launch_bounds__(256) void k1_xw(const float* __restrict__ A,
                                             const float* __restrict__ X,
                                             const float* __restrict__ W1,
                                             unsigned short* __restrict__ Abf,
                                             unsigned short* __restrict__ XWpb) {
    __shared__ __align__(16) unsigned short Ab[64][40];
    __shared__ __align__(16) unsigned short Bb[64][40];
    const int tid = threadIdx.x;
    const int bid = blockIdx.x + blockIdx.y * 32 + blockIdx.z * 128;   // 0..511
    // prologue: convert A (1048576 float4 units) with the whole grid
    for (int v = bid * 256 + tid; v < 1048576; v += 131072) {
        float4 f = ((const float4*)A)[v];
        short4 h;
        h.x = (short)f2bf(f.x); h.y = (short)f2bf(f.y);
        h.z = (short)f2bf(f.z); h.w = (short)f2bf(f.w);
        ((short4*)Abf)[v] = h;
    }
    const int n0 = blockIdx.x * 64;
    const int h0 = blockIdx.y * 64;
    const int ks = blockIdx.z;          // 0..3, K chunk of 128
    const int lane = tid & 63, wave = tid >> 6;
    const int wm = wave >> 1, wn = wave & 1;
    const int lm = lane & 15, lk = (lane >> 4) * 8;
    const int sr = tid >> 2, sc = (tid & 3) * 8;
    f32x4 acc[2][2] = {};
    for (int it = 0; it < 4; ++it) {
        int kk = ks * 128 + it * 32;
        *(uint4*)&Ab[sr][sc] = cvt8u(W1 + (size_t)(h0 + sr) * DD + kk + sc);
        *(uint4*)&Bb[sr][sc] = cvt8u(X  + (size_t)(n0 + sr) * DD + kk + sc);
        __syncthreads();
        short8 a0 = *(const short8*)&Ab[wm * 32 + lm][lk];
        short8 a1 = *(const short8*)&Ab[wm * 32 + 16 + lm][lk];
        short8 b0 = *(const short8*)&Bb[wn * 32 + lm][lk];
        short8 b1 = *(const short8*)&Bb[wn * 32 + 16 + lm][lk];
        acc[0][0] = __builtin_amdgcn_mfma_f32_16x16x32_bf16(a0, b0, acc[0][0], 0, 0, 0);
        acc[0][1] = __builtin_amdgcn_mfma_f32_16x16x32_bf16(a0, b1, acc[0][1], 0, 0, 0);
        acc[1][0] = __builtin_amdgcn_mfma_f32_16x16x32_bf16(a1, b0, acc[1][0], 0, 0, 0);
        acc[1][1] = __builtin_amdgcn_mfma_f32_16x16x32_bf16(a1, b1, acc[1][1], 0, 0, 0);
        __syncthreads();
    }
    unsigned short* outp = XWpb + (size_t)ks * 524288;
    #pragma unroll
    for (int mi = 0; mi < 2; ++mi)
        #pragma unroll
        for (int ni = 0; ni < 2; ++ni)
            #pragma unroll
            for (int r = 0; r < 4; ++r) {
                int row = h0 + wm * 32 + mi * 16 + (lane >> 4) * 4 + r;
                int col = n0 + wn * 32 + ni * 16 + lm;
                outp[(size_t)row * NNODE + col] = f2bf(acc[mi][ni][r]);
            }
}

// ---- K2: Hp[s][m][h] = fp32 partial A @ XW (splitK=8); B = sum of 4 XWpb --------
// grid (32 m, 4 h, 8 ks) = 1024 blocks (4/CU), K chunk 256 (8 iters of 32).
__global__ __launch_bounds__(256) void k2_h(const unsigned short* __restrict__ Abf,
                                            const unsigned short* __restrict__ XWpb,
                                            float* __restrict__ Hp) {
    __shared__ __align__(16) unsigned short Ab[64][40];
    __shared__ __align__(16) unsigned short Bb[64][40];
    const int tid = threadIdx.x;
    const int m0 = blockIdx.x * 64;
    const int n0 = blockIdx.y * 64;     // h cols
    const int ks = blockIdx.z;          // 0..7, node-K chunk of 256
    const int lane = tid & 63, wave = tid >> 6;
    const int wm = wave >> 1, wn = wave & 1;
    const int lm = lane & 15, lk = (lane >> 4) * 8;
    const int sr = tid >> 2, sc = (tid & 3) * 8;
    f32x4 acc[2][2] = {};
    for (int it = 0; it < 8; ++it) {
        int kk = ks * 256 + it * 32;
        *(uint4*)&Ab[sr][sc] = *(const uint4*)(Abf + (size_t)(m0 + sr) * NNODE + kk + sc);
        *(uint4*)&Bb[sr][sc] = sum4bf(XWpb, (size_t)(n0 + sr) * NNODE + kk + sc);
        __syncthreads();
        short8 a0 = *(const short8*)&Ab[wm * 32 + lm][lk];
        short8 a1 = *(const short8*)&Ab[wm * 32 + 16 + lm][lk];
        short8 b0 = *(const short8*)&Bb[wn * 32 + lm][lk];
        short8 b1 = *(const short8*)&Bb[wn * 32 + 16 + lm][lk];
        acc[0][0] = __builtin_amdgcn_mfma_f32_16x16x32_bf16(a0, b0, acc[0][0], 0, 0, 0);
        acc[0][1] = __builtin_amdgcn_mfma_f32_16x16x32_bf16(a0, b1, acc[0][1], 0, 0, 0);
        acc[1][0] = __builtin_amdgcn_mfma_f32_16x16x32_bf16(a1, b0, acc[1][0], 0, 0, 0);
        acc[1][1] = __builtin_amdgcn_mfma_f32_16x16x32_bf16(a1, b1, acc[1][1], 0, 0, 0);
        __syncthreads();
    }
    float* outp = Hp + (size_t)ks * 524288;
    #pragma unroll
    for (int mi = 0; mi < 2; ++mi)
        #pragma unroll
        for (int ni = 0; ni < 2; ++ni)
            #pragma unroll
            for (int r = 0; r < 4; ++r) {
                int row = m0 + wm * 32 + mi * 16 + (lane >> 4) * 4 + r;
                int col = n0 + wn * 32 + ni * 16 + lm;
                outp[(size_t)row * HHID + col] = acc[mi][ni][r];
            }
}

// ---- K3: Gt[j][n] = bf16( sum_d leaky(sum_s Hp[s][n][d] + b1[d]) * Wcat[j][d] ) -
__global__ __launch_bounds__(256) void k3_g(const float* __restrict__ Hp,
                                            const float* __restrict__ b1,
                                            const float* __restrict__ Wmu,
                                            const float* __restrict__ Wlv,
                                            unsigned short* __restrict__ Gt) {
    __shared__ float Hs[8][260];
    __shared__ float Ws[32][260];
    const int tid = threadIdx.x;
    const int n0 = blockIdx.x * 8;
    #pragma unroll
    for (int s = 0; s < 8; ++s) {
        int idx = tid + s * 256;            // float4 units, 0..2047
        int row = idx >> 6, c = (idx & 63) * 4;
        const float* src = (row < 16) ? (Wmu + (size_t)row * HHID)
                                      : (Wlv + (size_t)(row - 16) * HHID);
        *(float4*)&Ws[row][c] = *(const float4*)(src + c);
    }
    {   // stage 8 activated H rows: sum 8 partials + bias + leaky
        int r = tid >> 5, seg = tid & 31;
        int d = seg * 8;
        size_t off = (size_t)(n0 + r) * HHID + d;
        #pragma unroll
        for (int t = 0; t < 2; ++t) {
            float4 o = *(const float4*)(b1 + d + t * 4);
            #pragma unroll
            for (int s = 0; s < 8; ++s) {
                float4 v = *(const float4*)(Hp + off + (size_t)s * 524288 + t * 4);
                o.x += v.x; o.y += v.y; o.z += v.z; o.w += v.w;
            }
            o.x = fmaxf(o.x, 0.01f * o.x);
            o.y = fmaxf(o.y, 0.01f * o.y);
            o.z = fmaxf(o.z, 0.01f * o.z);
            o.w = fmaxf(o.w, 0.01f * o.w);
            *(float4*)&Hs[r][d + t * 4] = o;
        }
    }
    __syncthreads();
    const int r = tid >> 5, j = tid & 31;
    float acc = 0.f;
    #pragma unroll 8
    for (int d4 = 0; d4 < 64; ++d4) {
        float4 a = *(const float4*)&Hs[r][d4 * 4];
        float4 b = *(const float4*)&Ws[j][d4 * 4];
        acc += a.x * b.x + a.y * b.y + a.z * b.z + a.w * b.w;
    }
    Gt[(size_t)j * NNODE + n0 + r] = f2bf(acc);
}

// ---- K4: Mp[s][m][c] = partial A @ G (MFMA, splitK=16) --------------------------
// grid (32 m, 16 ks) = 512 blocks (2/CU), K chunk 128 (4 iters of 32).
__global__ __launch_bounds__(256) void k4_m(const unsigned short* __restrict__ Abf,
                                            const unsigned short* __restrict__ Gt,
                                            float* __restrict__ Mp) {
    __shared__ __align__(16) unsigned short Ab[64][40];
    __shared__ __align__(16) unsigned short Bb[32][40];
    const int tid = threadIdx.x;
    const int m0 = blockIdx.x * 64;
    const int ks = blockIdx.y;          // 0..15, K chunk of 128
    const int lane = tid & 63, wave = tid >> 6;
    const int lm = lane & 15, lk = (lane >> 4) * 8;
    const int sr = tid >> 2, sc = (tid & 3) * 8;
    f32x4 acc[2] = {};
    for (int it = 0; it < 4; ++it) {
        int kk = ks * 128 + it * 32;
        *(uint4*)&Ab[sr][sc] = *(const uint4*)(Abf + (size_t)(m0 + sr) * NNODE + kk + sc);
        if (tid < 128) {
            int row = tid >> 2, c = (tid & 3) * 8;
            *(uint4*)&Bb[row][c] = *(const uint4*)(Gt + (size_t)row * NNODE + kk + c);
        }
        __syncthreads();
        short8 a  = *(const short8*)&Ab[wave * 16 + lm][lk];
        short8 b0 = *(const short8*)&Bb[lm][lk];
        short8 b1 = *(const short8*)&Bb[16 + lm][lk];
        acc[0] = __builtin_amdgcn_mfma_f32_16x16x32_bf16(a, b0, acc[0], 0, 0, 0);
        acc[1] = __builtin_amdgcn_mfma_f32_16x16x32_bf16(a, b1, acc[1], 0, 0, 0);
        __syncthreads();
    }
    float* outp = Mp + (size_t)ks * 65536;
    #pragma unroll
    for (int ni = 0; ni < 2; ++ni)
        #pragma unroll
        for (int r = 0; r < 4; ++r) {
            int row = m0 + wave * 16 + (lane >> 4) * 4 + r;
            int col = ni * 16 + lm;
            outp[(size_t)row * H2 + col] = acc[ni][r];
        }
}

// ---- K5: reduce Mp(16); mu/logvar; Z; P', Q, WP/WQ ------------------------------
__global__ __launch_bounds__(256) void k5_z(const float* __restrict__ Mp,
                                            const float* __restrict__ bmu,
                                            const float* __restrict__ blv,
                                            const float* __restrict__ eps,
                                            const float* __restrict__ Wd1,
                                            const float* __restrict__ bd1,
                                            const float* __restrict__ Wd2,
                                            float* __restrict__ out_mu,
                                            float* __restrict__ out_lv,
                                            float* __restrict__ Pp,
                                            float* __restrict__ Qq,
                                            float* __restrict__ WP,
                                            float* __restrict__ WQ) {
    __shared__ float Zs[16][16];
    __shared__ float Psh[16][32];
    __shared__ float Qsh[16][32];
    const int tid = threadIdx.x;
    const int n0 = blockIdx.x * 16;
    {
        int nl = tid >> 4, l = tid & 15;
        int n = n0 + nl;
        float m = bmu[l], lv = blv[l];
        #pragma unroll
        for (int s = 0; s < 16; ++s) {
            m  += Mp[(size_t)s * 65536 + (size_t)n * H2 + l];
            lv += Mp[(size_t)s * 65536 + (size_t)n * H2 + 16 + l];
        }
        out_mu[(size_t)n * LLAT + l] = m;
        out_lv[(size_t)n * LLAT + l] = lv;
        Zs[nl][l] = m + eps[(size_t)n * LLAT + l] * __expf(0.5f * lv);
    }
    __syncthreads();
    #pragma unroll
    for (int p = 0; p < 2; ++p) {
        int idx = tid + p * 256;            // 0..511
        int nl = idx >> 5, o = idx & 31;
        int n = n0 + nl;
        float ap = bd1[o], aq = 0.f;
        #pragma unroll
        for (int l = 0; l < 16; ++l) {
            float z = Zs[nl][l];
            ap = fmaf(z, Wd1[o * H2 + l],      ap);
            aq = fmaf(z, Wd1[o * H2 + 16 + l], aq);
        }
        Pp[(size_t)n * H2 + o] = ap;
        Qq[(size_t)n * H2 + o] = aq;
        Psh[nl][o] = ap;
        Qsh[nl][o] = aq;
    }
    __syncthreads();
    if (tid < 32) {
        int nl = tid & 15, sel = tid >> 4;
        float a = 0.f;
        if (sel == 0) {
            #pragma unroll
            for (int o = 0; o < 32; ++o) a = fmaf(Wd2[o], Psh[nl][o], a);
            WP[n0 + nl] = a;
        } else {
            #pragma unroll
            for (int o = 0; o < 32; ++o) a = fmaf(Wd2[o], Qsh[nl][o], a);
            WQ[n0 + nl] = a;
        }
    }
}

// ---- K6: decoder via leaky(x)=0.505x+0.495|x|; 32 i-rows x 64 j-cols per block --
__global__ __launch_bounds__(256) void k6_dec(const float* __restrict__ Pp,
                                              const float* __restrict__ Qq,
                                              const float* __restrict__ WP,
                                              const float* __restrict__ WQ,
                                              const float* __restrict__ Wd2,
                                              const float* __restrict__ bd2,
                                              float* __restrict__ Apred) {
    __shared__ float Qt[32][68];   // transposed Q tile, padded
    __shared__ float Ws2[32];
    __shared__ float WQs[64];
    const int tid = threadIdx.x;
    const int j0 = blockIdx.x * 64, i0 = blockIdx.y * 32;
    #pragma unroll
    for (int s = 0; s < 8; ++s) {
        int idx = tid + s * 256;            // 0..2047
        int j = idx >> 5, o = idx & 31;
        Qt[o][j] = Qq[(size_t)(j0 + j) * H2 + o];
    }
    if (tid < 32) Ws2[tid] = Wd2[tid];
    if (tid >= 64 && tid < 128) WQs[tid - 64] = WQ[j0 + tid - 64];
    __syncthreads();
    const float b2 = bd2[0];
    const int jq = tid & 15;
    const float4 wq = *(const float4*)&WQs[jq * 4];
    #pragma unroll
    for (int sub = 0; sub < 2; ++sub) {
        const int i = i0 + sub * 16 + (tid >> 4);
        float p[32];
        const float4* P4 = (const float4*)(Pp + (size_t)i * H2);
        #pragma unroll
        for (int c = 0; c < 8; ++c) {
            float4 v = P4[c];
            p[c * 4] = v.x; p[c * 4 + 1] = v.y; p[c * 4 + 2] = v.z; p[c * 4 + 3] = v.w;
        }
        const float WPi = WP[i];
        f32x4 acc = {0.f, 0.f, 0.f, 0.f};   // sum_o w*|P+Q|
        #pragma unroll
        for (int o = 0; o < 32; ++o) {
            float4 q = *(const float4*)&Qt[o][jq * 4];
            float w = Ws2[o], po = p[o];
            acc[0] = fmaf(w, fabsf(po + q.x), acc[0]);
            acc[1] = fmaf(w, fabsf(po + q.y), acc[1]);
            acc[2] = fmaf(w, fabsf(po + q.z), acc[2]);
            acc[3] = fmaf(w, fabsf(po + q.w), acc[3]);
        }
        const float base = fmaf(0.505f, WPi, b2);
        float4 r;
        float l0 = fmaf(0.505f, wq.x, fmaf(0.495f, acc[0], base));
        float l1 = fmaf(0.505f, wq.y, fmaf(0.495f, acc[1], base));
        float l2 = fmaf(0.505f, wq.z, fmaf(0.495f, acc[2], base));
        float l3 = fmaf(0.505f, wq.w, fmaf(0.495f, acc[3], base));
        r.x = 1.f / (1.f + __expf(-l0));
        r.y = 1.f / (1.f + __expf(-l1));
        r.z = 1.f / (1.f + __expf(-l2));
        r.w = 1.f / (1.f + __expf(-l3));
        *(float4*)(Apred + (size_t)i * NNODE + j0 + jq * 4) = r;
    }
}

extern "C" void kernel_launch(void* const* d_in, const int* in_sizes, int n_in,
                              void* d_out, int out_size, void* d_ws, size_t ws_size,
                              hipStream_t stream) {
    const float* A   = (const float*)d_in[0];
    const float* X   = (const float*)d_in[1];
    const float* eps = (const float*)d_in[2];
    const float* W1  = (const float*)d_in[3];
    const float* b1  = (const float*)d_in[4];
    const float* Wmu = (const float*)d_in[5];
    const float* bmu = (const float*)d_in[6];
    const float* Wlv = (const float*)d_in[7];
    const float* blv = (const float*)d_in[8];
    const float* Wd1 = (const float*)d_in[9];
    const float* bd1 = (const float*)d_in[10];
    const float* Wd2 = (const float*)d_in[11];
    const float* bd2 = (const float*)d_in[12];
    float* out = (float*)d_out;
    char* ws = (char*)d_ws;

    // workspace carve (~34.2 MB), all buffers fully overwritten each call
    unsigned short* Abf  = (unsigned short*)(ws);               //  8,388,608
    unsigned short* XWpb = (unsigned short*)(ws + 8388608);     //  4,194,304 (4 x 1MB bf16)
    float*          Hp   = (float*)(ws + 12582912);             // 16,777,216 (8 x 2MB)
    unsigned short* Gt   = (unsigned short*)(ws + 29360128);    //    131,072
    float*          Mp   = (float*)(ws + 29491200);             //  4,194,304 (16 x 256KB)
    float*          Pp   = (float*)(ws + 33685504);             //    262,144
    float*          Qq   = (float*)(ws + 33947648);             //    262,144
    float*          WP   = (float*)(ws + 34209792);             //      8,192
    float*          WQ   = (float*)(ws + 34217984);             //      8,192

    float* out_mu = out + (size_t)NNODE * NNODE;
    float* out_lv = out_mu + NNODE * LLAT;

    k1_xw <<<dim3(32, 4, 4), 256, 0, stream>>>(A, X, W1, Abf, XWpb);
    k2_h  <<<dim3(32, 4, 8), 256, 0, stream>>>(Abf, XWpb, Hp);
    k3_g  <<<256,            256, 0, stream>>>(Hp, b1, Wmu, Wlv, Gt);
    k4_m  <<<dim3(32, 16),   256, 0, stream>>>(Abf, Gt, Mp);
    k5_z  <<<128,            256, 0, stream>>>(Mp, bmu, blv, eps, Wd1, bd1, Wd2,
                                               out_mu, out_lv, Pp, Qq, WP, WQ);
    k6_dec<<<dim3(32, 64),   256, 0, stream>>>(Pp, Qq, WP, WQ, Wd2, bd2, out);
}

// Round 10
// 141.362 us; speedup vs baseline: 1.1959x; 1.1959x over previous
//
#include <hip/hip_runtime.h>

#define NNODE 2048
#define DD    512
#define HHID  256
#define LLAT  16
#define H2    32   // 2L

typedef __attribute__((ext_vector_type(8))) short  short8;
typedef __attribute__((ext_vector_type(4))) float  f32x4;

__device__ __forceinline__ unsigned short f2bf(float x) {
    unsigned int u = __float_as_uint(x);
    unsigned int r = (u + 0x7fffu + ((u >> 16) & 1u)) >> 16;  // RNE
    return (unsigned short)r;
}
__device__ __forceinline__ float bf2f(unsigned short u) {
    return __uint_as_float(((unsigned int)u) << 16);
}

// ---------------- T0: convert A, X, W1 to bf16 (grid-stride over float4) ---------
__global__ __launch_bounds__(256) void t0_cvt(const float* __restrict__ A,
                                              const float* __restrict__ X,
                                              const float* __restrict__ W1,
                                              unsigned short* __restrict__ Abf,
                                              unsigned short* __restrict__ Xbf,
                                              unsigned short* __restrict__ W1bf) {
    const int NT = 1343488;   // 1048576 (A) + 262144 (X) + 32768 (W1) float4 units
    for (int v = blockIdx.x * 256 + threadIdx.x; v < NT; v += gridDim.x * 256) {
        const float* src; unsigned short* dst; int off;
        if (v < 1048576)      { src = A;  dst = Abf;  off = v; }
        else if (v < 1310720) { src = X;  dst = Xbf;  off = v - 1048576; }
        else                  { src = W1; dst = W1bf; off = v - 1310720; }
        float4 f = ((const float4*)src)[off];
        short4 h;
        h.x = (short)f2bf(f.x); h.y = (short)f2bf(f.y);
        h.z = (short)f2bf(f.z); h.w = (short)f2bf(f.w);
        ((short4*)dst)[off] = h;
    }
}

// ---------------- T1: XWp[s][h][n] = partial W1bf @ Xbf^T  (MFMA, splitK=4) ------
__global__ __launch_bounds__(256) void t1_mfma(const unsigned short* __restrict__ W1bf,
                                               const unsigned short* __restrict__ Xbf,
                                               float* __restrict__ XWp) {
    __shared__ __align__(16) unsigned short Ab[64][40];
    __shared__ __align__(16) unsigned short Bb[64][40];
    const int tid = threadIdx.x;
    const int n0 = blockIdx.x * 64;
    const int h0 = blockIdx.y * 64;
    const int ks = blockIdx.z;          // 0..3, K chunk of 128
    const int lane = tid & 63, wave = tid >> 6;
    const int wm = wave >> 1, wn = wave & 1;
    const int lm = lane & 15, lk = (lane >> 4) * 8;
    const int sr = tid >> 2, sc = (tid & 3) * 8;
    f32x4 acc[2][2] = {};
    for (int it = 0; it < 4; ++it) {
        int kk = ks * 128 + it * 32;
        *(uint4*)&Ab[sr][sc] = *(const uint4*)(W1bf + (size_t)(h0 + sr) * DD + kk + sc);
        *(uint4*)&Bb[sr][sc] = *(const uint4*)(Xbf  + (size_t)(n0 + sr) * DD + kk + sc);
        __syncthreads();
        short8 a0 = *(const short8*)&Ab[wm * 32 + lm][lk];
        short8 a1 = *(const short8*)&Ab[wm * 32 + 16 + lm][lk];
        short8 b0 = *(const short8*)&Bb[wn * 32 + lm][lk];
        short8 b1 = *(const short8*)&Bb[wn * 32 + 16 + lm][lk];
        acc[0][0] = __builtin_amdgcn_mfma_f32_16x16x32_bf16(a0, b0, acc[0][0], 0, 0, 0);
        acc[0][1] = __builtin_amdgcn_mfma_f32_16x16x32_bf16(a0, b1, acc[0][1], 0, 0, 0);
        acc[1][0] = __builtin_amdgcn_mfma_f32_16x16x32_bf16(a1, b0, acc[1][0], 0, 0, 0);
        acc[1][1] = __builtin_amdgcn_mfma_f32_16x16x32_bf16(a1, b1, acc[1][1], 0, 0, 0);
        __syncthreads();
    }
    float* outp = XWp + (size_t)ks * 524288;
    #pragma unroll
    for (int mi = 0; mi < 2; ++mi)
        #pragma unroll
        for (int ni = 0; ni < 2; ++ni)
            #pragma unroll
            for (int r = 0; r < 4; ++r) {
                int row = h0 + wm * 32 + mi * 16 + (lane >> 4) * 4 + r;
                int col = n0 + wn * 32 + ni * 16 + lm;
                outp[(size_t)row * NNODE + col] = acc[mi][ni][r];
            }
}

// ---------------- T1r: XWt = bf16(sum_s XWp[s]) ----------------------------------
__global__ __launch_bounds__(256) void t1r(const float* __restrict__ XWp,
                                           unsigned short* __restrict__ XWt) {
    int v = blockIdx.x * 256 + threadIdx.x;      // 131072 float4 units
    const float4* p = (const float4*)XWp;
    float4 a = p[v];
    float4 b = p[v + 131072];
    float4 c = p[v + 262144];
    float4 d = p[v + 393216];
    float4 s;
    s.x = (a.x + b.x) + (c.x + d.x);
    s.y = (a.y + b.y) + (c.y + d.y);
    s.z = (a.z + b.z) + (c.z + d.z);
    s.w = (a.w + b.w) + (c.w + d.w);
    short4 h;
    h.x = (short)f2bf(s.x); h.y = (short)f2bf(s.y);
    h.z = (short)f2bf(s.z); h.w = (short)f2bf(s.w);
    ((short4*)XWt)[v] = h;
}

// ---------------- T2: Hp[s][m][d] = partial A @ XW  (MFMA, splitK=4) -------------
__global__ __launch_bounds__(256) void t2_mfma(const unsigned short* __restrict__ Abf,
                                               const unsigned short* __restrict__ XWt,
                                               float* __restrict__ Hp) {
    __shared__ __align__(16) unsigned short Ab[64][40];
    __shared__ __align__(16) unsigned short Bb[64][40];
    const int tid = threadIdx.x;
    const int m0 = blockIdx.x * 64;
    const int n0 = blockIdx.y * 64;
    const int ks = blockIdx.z;          // 0..3, K chunk of 512
    const int lane = tid & 63, wave = tid >> 6;
    const int wm = wave >> 1, wn = wave & 1;
    const int lm = lane & 15, lk = (lane >> 4) * 8;
    const int sr = tid >> 2, sc = (tid & 3) * 8;
    f32x4 acc[2][2] = {};
    for (int it = 0; it < 16; ++it) {
        int kk = ks * 512 + it * 32;
        *(uint4*)&Ab[sr][sc] = *(const uint4*)(Abf + (size_t)(m0 + sr) * NNODE + kk + sc);
        *(uint4*)&Bb[sr][sc] = *(const uint4*)(XWt + (size_t)(n0 + sr) * NNODE + kk + sc);
        __syncthreads();
        short8 a0 = *(const short8*)&Ab[wm * 32 + lm][lk];
        short8 a1 = *(const short8*)&Ab[wm * 32 + 16 + lm][lk];
        short8 b0 = *(const short8*)&Bb[wn * 32 + lm][lk];
        short8 b1 = *(const short8*)&Bb[wn * 32 + 16 + lm][lk];
        acc[0][0] = __builtin_amdgcn_mfma_f32_16x16x32_bf16(a0, b0, acc[0][0], 0, 0, 0);
        acc[0][1] = __builtin_amdgcn_mfma_f32_16x16x32_bf16(a0, b1, acc[0][1], 0, 0, 0);
        acc[1][0] = __builtin_amdgcn_mfma_f32_16x16x32_bf16(a1, b0, acc[1][0], 0, 0, 0);
        acc[1][1] = __builtin_amdgcn_mfma_f32_16x16x32_bf16(a1, b1, acc[1][1], 0, 0, 0);
        __syncthreads();
    }
    float* outp = Hp + (size_t)ks * 524288;
    #pragma unroll
    for (int mi = 0; mi < 2; ++mi)
        #pragma unroll
        for (int ni = 0; ni < 2; ++ni)
            #pragma unroll
            for (int r = 0; r < 4; ++r) {
                int row = m0 + wm * 32 + mi * 16 + (lane >> 4) * 4 + r;
                int col = n0 + wn * 32 + ni * 16 + lm;
                outp[(size_t)row * HHID + col] = acc[mi][ni][r];
            }
}

// ---------------- T2r: Hbf = bf16(leaky(sum_s Hp[s] + b1)) -----------------------
__global__ __launch_bounds__(256) void t2r(const float* __restrict__ Hp,
                                           const float* __restrict__ b1,
                                           unsigned short* __restrict__ Hbf) {
    int v = blockIdx.x * 256 + threadIdx.x;      // 131072 float4 units
    const float4* p = (const float4*)Hp;
    float4 a = p[v];
    float4 b = p[v + 131072];
    float4 c = p[v + 262144];
    float4 d = p[v + 393216];
    int dcol = (v & 63) * 4;
    float4 bb = *(const float4*)(b1 + dcol);
    float4 s;
    s.x = (a.x + b.x) + (c.x + d.x) + bb.x;
    s.y = (a.y + b.y) + (c.y + d.y) + bb.y;
    s.z = (a.z + b.z) + (c.z + d.z) + bb.z;
    s.w = (a.w + b.w) + (c.w + d.w) + bb.w;
    s.x = fmaxf(s.x, 0.01f * s.x);
    s.y = fmaxf(s.y, 0.01f * s.y);
    s.z = fmaxf(s.z, 0.01f * s.z);
    s.w = fmaxf(s.w, 0.01f * s.w);
    short4 h;
    h.x = (short)f2bf(s.x); h.y = (short)f2bf(s.y);
    h.z = (short)f2bf(s.z); h.w = (short)f2bf(s.w);
    ((short4*)Hbf)[v] = h;
}

// ---------------- T3: Gt[j][n] = bf16( sum_d Hbf[n][d] * Wcat[j][d] ) ------------
__global__ __launch_bounds__(256) void t3_g(const unsigned short* __restrict__ Hbf,
                                            const float* __restrict__ Wmu,
                                            const float* __restrict__ Wlv,
                                            unsigned short* __restrict__ Gt) {
    __shared__ float Hs[8][260];
    __shared__ float Ws[32][260];
    const int tid = threadIdx.x;
    const int n0 = blockIdx.x * 8;
    #pragma unroll
    for (int s = 0; s < 8; ++s) {
        int idx = tid + s * 256;            // float4 units, 0..2047
        int row = idx >> 6, c = (idx & 63) * 4;
        const float* src = (row < 16) ? (Wmu + (size_t)row * HHID)
                                      : (Wlv + (size_t)(row - 16) * HHID);
        *(float4*)&Ws[row][c] = *(const float4*)(src + c);
    }
    {
        int r = tid >> 5, seg = tid & 31;
        int d = seg * 8;
        ushort4 u0 = *(const ushort4*)(Hbf + (size_t)(n0 + r) * HHID + d);
        ushort4 u1 = *(const ushort4*)(Hbf + (size_t)(n0 + r) * HHID + d + 4);
        Hs[r][d + 0] = bf2f(u0.x); Hs[r][d + 1] = bf2f(u0.y);
        Hs[r][d + 2] = bf2f(u0.z); Hs[r][d + 3] = bf2f(u0.w);
        Hs[r][d + 4] = bf2f(u1.x); Hs[r][d + 5] = bf2f(u1.y);
        Hs[r][d + 6] = bf2f(u1.z); Hs[r][d + 7] = bf2f(u1.w);
    }
    __syncthreads();
    const int r = tid >> 5, j = tid & 31;
    float acc = 0.f;
    #pragma unroll 8
    for (int d4 = 0; d4 < 64; ++d4) {
        float4 a = *(const float4*)&Hs[r][d4 * 4];
        float4 b = *(const float4*)&Ws[j][d4 * 4];
        acc += a.x * b.x + a.y * b.y + a.z * b.z + a.w * b.w;
    }
    Gt[(size_t)j * NNODE + n0 + r] = f2bf(acc);
}

// ---------------- T4: Mp[s][m][c] = partial A @ G  (MFMA, splitK=8) --------------
__global__ __launch_bounds__(256) void t4_mfma(const unsigned short* __restrict__ Abf,
                                               const unsigned short* __restrict__ Gt,
                                               float* __restrict__ Mp) {
    __shared__ __align__(16) unsigned short Ab[64][40];
    __shared__ __align__(16) unsigned short Bb[32][40];
    const int tid = threadIdx.x;
    const int m0 = blockIdx.x * 64;
    const int ks = blockIdx.y;          // 0..7, K chunk of 256
    const int lane = tid & 63, wave = tid >> 6;
    const int lm = lane & 15, lk = (lane >> 4) * 8;
    const int sr = tid >> 2, sc = (tid & 3) * 8;
    f32x4 acc[2] = {};
    for (int it = 0; it < 8; ++it) {
        int kk = ks * 256 + it * 32;
        *(uint4*)&Ab[sr][sc] = *(const uint4*)(Abf + (size_t)(m0 + sr) * NNODE + kk + sc);
        if (tid < 128) {
            int row = tid >> 2, c = (tid & 3) * 8;
            *(uint4*)&Bb[row][c] = *(const uint4*)(Gt + (size_t)row * NNODE + kk + c);
        }
        __syncthreads();
        short8 a  = *(const short8*)&Ab[wave * 16 + lm][lk];
        short8 b0 = *(const short8*)&Bb[lm][lk];
        short8 b1 = *(const short8*)&Bb[16 + lm][lk];
        acc[0] = __builtin_amdgcn_mfma_f32_16x16x32_bf16(a, b0, acc[0], 0, 0, 0);
        acc[1] = __builtin_amdgcn_mfma_f32_16x16x32_bf16(a, b1, acc[1], 0, 0, 0);
        __syncthreads();
    }
    float* outp = Mp + (size_t)ks * 65536;
    #pragma unroll
    for (int ni = 0; ni < 2; ++ni)
        #pragma unroll
        for (int r = 0; r < 4; ++r) {
            int row = m0 + wave * 16 + (lane >> 4) * 4 + r;
            int col = ni * 16 + lm;
            outp[(size_t)row * H2 + col] = acc[ni][r];
        }
}

// ---------------- T5: reduce Mp; mu/logvar; Z; P', Q, and WP/WQ ------------------
__global__ __launch_bounds__(256) void t5_z(const float* __restrict__ Mp,
                                            const float* __restrict__ bmu,
                                            const float* __restrict__ blv,
                                            const float* __restrict__ eps,
                                            const float* __restrict__ Wd1,
                                            const float* __restrict__ bd1,
                                            const float* __restrict__ Wd2,
                                            float* __restrict__ out_mu,
                                            float* __restrict__ out_lv,
                                            float* __restrict__ Pp,
                                            float* __restrict__ Qq,
                                            float* __restrict__ WP,
                                            float* __restrict__ WQ) {
    __shared__ float Zs[16][16];
    __shared__ float Psh[16][32];
    __shared__ float Qsh[16][32];
    const int tid = threadIdx.x;
    const int n0 = blockIdx.x * 16;
    {
        int nl = tid >> 4, l = tid & 15;
        int n = n0 + nl;
        float m = bmu[l], lv = blv[l];
        #pragma unroll
        for (int s = 0; s < 8; ++s) {
            m  += Mp[(size_t)s * 65536 + (size_t)n * H2 + l];
            lv += Mp[(size_t)s * 65536 + (size_t)n * H2 + 16 + l];
        }
        out_mu[(size_t)n * LLAT + l] = m;
        out_lv[(size_t)n * LLAT + l] = lv;
        Zs[nl][l] = m + eps[(size_t)n * LLAT + l] * __expf(0.5f * lv);
    }
    __syncthreads();
    #pragma unroll
    for (int p = 0; p < 2; ++p) {
        int idx = tid + p * 256;            // 0..511
        int nl = idx >> 5, o = idx & 31;
        int n = n0 + nl;
        float ap = bd1[o], aq = 0.f;
        #pragma unroll
        for (int l = 0; l < 16; ++l) {
            float z = Zs[nl][l];
            ap = fmaf(z, Wd1[o * H2 + l],      ap);
            aq = fmaf(z, Wd1[o * H2 + 16 + l], aq);
        }
        Pp[(size_t)n * H2 + o] = ap;
        Qq[(size_t)n * H2 + o] = aq;
        Psh[nl][o] = ap;
        Qsh[nl][o] = aq;
    }
    __syncthreads();
    if (tid < 32) {
        int nl = tid & 15, sel = tid >> 4;
        float a = 0.f;
        if (sel == 0) {
            #pragma unroll
            for (int o = 0; o < 32; ++o) a = fmaf(Wd2[o], Psh[nl][o], a);
            WP[n0 + nl] = a;
        } else {
            #pragma unroll
            for (int o = 0; o < 32; ++o) a = fmaf(Wd2[o], Qsh[nl][o], a);
            WQ[n0 + nl] = a;
        }
    }
}

// ---------------- T6: decoder via leaky(x)=0.505x+0.495|x| decomposition ---------
__global__ __launch_bounds__(256) void t6_dec(const float* __restrict__ Pp,
                                              const float* __restrict__ Qq,
                                              const float* __restrict__ WP,
                                              const float* __restrict__ WQ,
                                              const float* __restrict__ Wd2,
                                              const float* __restrict__ bd2,
                                              float* __restrict__ Apred) {
    __shared__ float Qt[32][68];   // transposed Q tile, padded
    __shared__ float Ws2[32];
    __shared__ float WQs[64];
    const int tid = threadIdx.x;
    const int j0 = blockIdx.x * 64, i0 = blockIdx.y * 16;
    #pragma unroll
    for (int s = 0; s < 8; ++s) {
        int idx = tid + s * 256;            // 0..2047
        int j = idx >> 5, o = idx & 31;
        Qt[o][j] = Qq[(size_t)(j0 + j) * H2 + o];
    }
    if (tid < 32) Ws2[tid] = Wd2[tid];
    if (tid >= 64 && tid < 128) WQs[tid - 64] = WQ[j0 + tid - 64];
    const int i = i0 + (tid >> 4);
    const int jq = tid & 15;
    float p[32];
    const float4* P4 = (const float4*)(Pp + (size_t)i * H2);
    #pragma unroll
    for (int c = 0; c < 8; ++c) {
        float4 v = P4[c];
        p[c * 4] = v.x; p[c * 4 + 1] = v.y; p[c * 4 + 2] = v.z; p[c * 4 + 3] = v.w;
    }
    const float WPi = WP[i];
    __syncthreads();
    f32x4 acc = {0.f, 0.f, 0.f, 0.f};   // sum_o w*|P+Q|
    #pragma unroll
    for (int o = 0; o < 32; ++o) {
        float4 q = *(const float4*)&Qt[o][jq * 4];
        float w = Ws2[o], po = p[o];
        acc[0] = fmaf(w, fabsf(po + q.x), acc[0]);
        acc[1] = fmaf(w, fabsf(po + q.y), acc[1]);
        acc[2] = fmaf(w, fabsf(po + q.z), acc[2]);
        acc[3] = fmaf(w, fabsf(po + q.w), acc[3]);
    }
    float4 wq = *(const float4*)&WQs[jq * 4];
    const float base = fmaf(0.505f, WPi, bd2[0]);
    float4 r;
    float l0 = fmaf(0.505f, wq.x, fmaf(0.495f, acc[0], base));
    float l1 = fmaf(0.505f, wq.y, fmaf(0.495f, acc[1], base));
    float l2 = fmaf(0.505f, wq.z, fmaf(0.495f, acc[2], base));
    float l3 = fmaf(0.505f, wq.w, fmaf(0.495f, acc[3], base));
    r.x = 1.f / (1.f + __expf(-l0));
    r.y = 1.f / (1.f + __expf(-l1));
    r.z = 1.f / (1.f + __expf(-l2));
    r.w = 1.f / (1.f + __expf(-l3));
    *(float4*)(Apred + (size_t)i * NNODE + j0 + jq * 4) = r;
}

extern "C" void kernel_launch(void* const* d_in, const int* in_sizes, int n_in,
                              void* d_out, int out_size, void* d_ws, size_t ws_size,
                              hipStream_t stream) {
    const float* A   = (const float*)d_in[0];
    const float* X   = (const float*)d_in[1];
    const float* eps = (const float*)d_in[2];
    const float* W1  = (const float*)d_in[3];
    const float* b1  = (const float*)d_in[4];
    const float* Wmu = (const float*)d_in[5];
    const float* bmu = (const float*)d_in[6];
    const float* Wlv = (const float*)d_in[7];
    const float* blv = (const float*)d_in[8];
    const float* Wd1 = (const float*)d_in[9];
    const float* bd1 = (const float*)d_in[10];
    const float* Wd2 = (const float*)d_in[11];
    const float* bd2 = (const float*)d_in[12];
    float* out = (float*)d_out;
    char* ws = (char*)d_ws;

    // workspace carve (~32.4 MB), all buffers fully overwritten each call
    unsigned short* Abf  = (unsigned short*)(ws);               //  8,388,608
    unsigned short* Xbf  = (unsigned short*)(ws + 8388608);     //  2,097,152
    unsigned short* W1bf = (unsigned short*)(ws + 10485760);    //    262,144
    float*          XWp  = (float*)(ws + 10747904);             //  8,388,608 (4 x 2MB)
    unsigned short* XWt  = (unsigned short*)(ws + 19136512);    //  1,048,576
    float*          Hp   = (float*)(ws + 20185088);             //  8,388,608 (4 x 2MB)
    unsigned short* Hbf  = (unsigned short*)(ws + 28573696);    //  1,048,576
    unsigned short* Gt   = (unsigned short*)(ws + 29622272);    //    131,072
    float*          Mp   = (float*)(ws + 29753344);             //  2,097,152 (8 x 256KB)
    float*          Pp   = (float*)(ws + 31850496);             //    262,144
    float*          Qq   = (float*)(ws + 32112640);             //    262,144
    float*          WP   = (float*)(ws + 32374784);             //      8,192
    float*          WQ   = (float*)(ws + 32382976);             //      8,192

    float* out_mu = out + (size_t)NNODE * NNODE;
    float* out_lv = out_mu + NNODE * LLAT;

    t0_cvt <<<2048,            256, 0, stream>>>(A, X, W1, Abf, Xbf, W1bf);
    t1_mfma<<<dim3(32, 4, 4),  256, 0, stream>>>(W1bf, Xbf, XWp);
    t1r    <<<512,             256, 0, stream>>>(XWp, XWt);
    t2_mfma<<<dim3(32, 4, 4),  256, 0, stream>>>(Abf, XWt, Hp);
    t2r    <<<512,             256, 0, stream>>>(Hp, b1, Hbf);
    t3_g   <<<256,             256, 0, stream>>>(Hbf, Wmu, Wlv, Gt);
    t4_mfma<<<dim3(32, 8),     256, 0, stream>>>(Abf, Gt, Mp);
    t5_z   <<<128,             256, 0, stream>>>(Mp, bmu, blv, eps, Wd1, bd1, Wd2,
                                                 out_mu, out_lv, Pp, Qq, WP, WQ);
    t6_dec <<<dim3(32, 128),   256, 0, stream>>>(Pp, Qq, WP, WQ, Wd2, bd2, out);
}